// Round 4
// baseline (379.331 us; speedup 1.0000x reference)
//
#include <hip/hip_runtime.h>
#include <math.h>

// Cone-beam forward projection (TIGRE Ax analogue).
// Volume: [B=2, NZ=96, NY=96, NX=96] f32, ZYX layout (x fastest).
// Output: [B=2, A=48, NV=96, NU=96] f32.
// One thread per ray; NS=96 samples.
//
// CORRECTNESS-CRITICAL: reference integrand is DISCONTINUOUS at cube faces.
// Position path replicates the reference's f32 op sequence exactly:
// contract(off), per-sample src + d*t, IEEE sqrt+div, f64-rounded trig.
// R4 change: branch-free inner body (clamped unconditional loads + select-
// masked accumulate, wave-uniform trip count) so the compiler can software-
// pipeline gathers across iterations (unroll 4). Accumulated values are
// bit-identical: masked-out samples add literal 0.0f, same as being skipped.

#define NZg 96
#define NYg 96
#define NXg 96
#define NVg 96
#define NUg 96
#define NAg 48
#define NSg 96
#define NBg 2

// 8-byte vector load with only 4-byte alignment guarantee
typedef float f2u __attribute__((ext_vector_type(2), aligned(4)));

__global__ __launch_bounds__(256) void coneproj_kernel(
    const float* __restrict__ vol, float* __restrict__ out) {
#pragma clang fp contract(off)
    const int idx = blockIdx.x * blockDim.x + threadIdx.x;
    // idx = ((b*NA + a)*NV + v)*NU + u   (u fastest -> coalesced out write)
    const int u   = idx % NUg;
    int tmp       = idx / NUg;
    const int v   = tmp % NVg;
    tmp          /= NVg;
    const int a   = tmp % NAg;
    const int b   = tmp / NAg;

    // theta = a * (f32(2*pi) / 48)   [jax linspace f32 semantics]
    const float dtheta = 6.2831855f / 48.0f;
    const float theta  = (float)a * dtheta;
    const float c = (float)cos((double)theta);
    const float s = (float)sin((double)theta);

    // source / detector pixel (x,y,z), ref op order, f32, no contraction
    const float srcx = 500.0f * c;
    const float srcy = 500.0f * s;
    const float uu = ((float)u - 47.5f) * 2.0f;
    const float vv = ((float)v - 47.5f) * 2.0f;
    const float pixx = (-500.0f * c) + uu * (-s);
    const float pixy = (-500.0f * s) + uu * c;
    const float pixz = vv;

    const float dx0 = pixx - srcx;
    const float dy0 = pixy - srcy;
    const float dz0 = pixz;
    const float nrm = sqrtf((dx0 * dx0 + dy0 * dy0) + dz0 * dz0);
    const float dx = dx0 / nrm;
    const float dy = dy0 / nrm;
    const float dz = dz0 / nrm;

    const float stepf = (float)1.7320508075688773;   // f32(2R/96)
    const float t0f   = (float)416.8615612366939;    // f32(DSO-R)

    // conservative AABB clip of sample range (skip-only; in-loop test is
    // authoritative)
    const float LO = -47.51f, HI = 47.51f;
    float tlo = -1e30f, thi = 1e30f;
    {
        const float o3[3] = {srcx, srcy, 0.0f};
        const float d3[3] = {dx, dy, dz};
        bool empty = false;
        #pragma unroll
        for (int ax = 0; ax < 3; ++ax) {
            const float oo = o3[ax], dd = d3[ax];
            if (fabsf(dd) > 1e-8f) {
                const float inv = 1.0f / dd;
                const float ta = (LO - oo) * inv;
                const float tb = (HI - oo) * inv;
                tlo = fmaxf(tlo, fminf(ta, tb));
                thi = fminf(thi, fmaxf(ta, tb));
            } else if (oo < LO || oo > HI) {
                empty = true;
            }
        }
        if (empty) { tlo = 1.0f; thi = 0.0f; }
    }
    int k0, k1;
    if (thi >= tlo) {
        k0 = (int)floorf((tlo - t0f) / stepf) - 2;
        k1 = (int)ceilf((thi - t0f) / stepf) + 2;
        k0 = max(k0, 0);
        k1 = min(k1, NSg - 1);
    } else {
        k0 = NSg; k1 = -1;  // empty (min/max-reduction friendly)
    }

    // wave-uniform loop bounds -> scalar loop branch, branch-free body
    int k0w = k0, k1w = k1;
    #pragma unroll
    for (int off = 32; off; off >>= 1) {
        k0w = min(k0w, __shfl_xor(k0w, off, 64));
        k1w = max(k1w, __shfl_xor(k1w, off, 64));
    }

    const float* __restrict__ volb = vol + (size_t)b * (NZg * NYg * NXg);

    float acc = 0.0f;
    #pragma unroll 4
    for (int k = k0w; k <= k1w; ++k) {
        const float tk = t0f + ((float)k + 0.5f) * stepf;
        const float ix = (srcx + dx * tk) + 47.5f;
        const float iy = (srcy + dy * tk) + 47.5f;
        const float iz = (dz * tk) + 47.5f;
        const bool valid = (ix >= 0.0f) & (ix <= 95.0f) &
                           (iy >= 0.0f) & (iy <= 95.0f) &
                           (iz >= 0.0f) & (iz <= 95.0f);
        // clamp for addressing only; when valid, clamped == original
        const float ixc = fminf(fmaxf(ix, 0.0f), 95.0f);
        const float iyc = fminf(fmaxf(iy, 0.0f), 95.0f);
        const float izc = fminf(fmaxf(iz, 0.0f), 95.0f);
        const int x0 = min((int)ixc, NXg - 2);
        const int y0 = min((int)iyc, NYg - 2);
        const int z0 = min((int)izc, NZg - 2);
        const float fx = ixc - (float)x0;
        const float fy = iyc - (float)y0;
        const float fz = izc - (float)z0;
        const int off0 = (z0 * NYg + y0) * NXg + x0;
        const f2u q00 = *(const f2u*)(volb + off0);
        const f2u q01 = *(const f2u*)(volb + off0 + NXg);
        const f2u q10 = *(const f2u*)(volb + off0 + NYg * NXg);
        const f2u q11 = *(const f2u*)(volb + off0 + NYg * NXg + NXg);
        const float c00 = q00.x + fx * (q00.y - q00.x);
        const float c01 = q01.x + fx * (q01.y - q01.x);
        const float c10 = q10.x + fx * (q10.y - q10.x);
        const float c11 = q11.x + fx * (q11.y - q11.x);
        const float c0  = c00 + fy * (c01 - c00);
        const float c1  = c10 + fy * (c11 - c10);
        const float tri = c0 + fz * (c1 - c0);
        acc += valid ? tri : 0.0f;
    }
    out[idx] = acc * stepf;
}

extern "C" void kernel_launch(void* const* d_in, const int* in_sizes, int n_in,
                              void* d_out, int out_size, void* d_ws, size_t ws_size,
                              hipStream_t stream) {
    const float* vol = (const float*)d_in[0];
    float* out = (float*)d_out;
    const int total = NBg * NAg * NVg * NUg;  // 884736 == out_size
    coneproj_kernel<<<total / 256, 256, 0, stream>>>(vol, out);
}